// Round 27
// baseline (105.428 us; speedup 1.0000x reference)
//
#include <hip/hip_runtime.h>
#include <hip/hip_bf16.h>

typedef __attribute__((ext_vector_type(4))) int   i32x4;
typedef __attribute__((ext_vector_type(8))) int   i32x8;
typedef __attribute__((ext_vector_type(16))) float f32x16;

#define C_DIM 512
#define SCALE 1.6487212707001282f            // exp(0.5)
#define S2LOG (SCALE * 1.4426950408889634f)  // exp(0.5) * log2(e)
#define Q4SCALE 16.0f                        // quantize q = x*16; MFMA scale 2^-4 (E8M0 123)

// e2m1 encode: codes 0..7 = {0,0.5,1,1.5,2,3,4,6}, bit3 = sign
__device__ __forceinline__ unsigned int fp4_enc(float v) {
  unsigned int s = (__float_as_uint(v) >> 28) & 8;
  float a = fabsf(v);
  unsigned int m;
  if      (a < 0.25f) m = 0;
  else if (a < 0.75f) m = 1;
  else if (a < 1.25f) m = 2;
  else if (a < 1.75f) m = 3;
  else if (a < 2.5f)  m = 4;
  else if (a < 3.5f)  m = 5;
  else if (a < 5.0f)  m = 6;
  else                m = 7;
  return s | m;
}

// -------- Kernel A: L2-normalize rows -> MX-fp4 (e2m1, global scale 2^-4) in
//          fragment-tiled layout; exact fp32 diag; zero sumexp.
// fp4 fragment (rb,kb) = 1KB at base (rb*8+kb)*1024 + lane*16;
// lane = 32*(k64half) + (row&31); nibble k'' at byte k''>>1, shift (k''&1)*4.
__global__ __launch_bounds__(128) void cossim_normalize_v3(
    const float* __restrict__ pred, const float* __restrict__ target,
    unsigned char* __restrict__ p4, unsigned char* __restrict__ t4,
    float* __restrict__ diag, float* __restrict__ sumexp) {
  const int n = blockIdx.x;
  const int t = threadIdx.x;  // 128 threads, 4 floats each = 512
  const float4* p4v = (const float4*)(pred + (size_t)n * C_DIM);
  const float4* q4v = (const float4*)(target + (size_t)n * C_DIM);
  float4 a = p4v[t];
  float4 b = q4v[t];
  float ssp = a.x*a.x + a.y*a.y + a.z*a.z + a.w*a.w;
  float sst = b.x*b.x + b.y*b.y + b.z*b.z + b.w*b.w;
  float dt  = a.x*b.x + a.y*b.y + a.z*b.z + a.w*b.w;
  #pragma unroll
  for (int off = 32; off > 0; off >>= 1) {
    ssp += __shfl_down(ssp, off);
    sst += __shfl_down(sst, off);
    dt  += __shfl_down(dt,  off);
  }
  __shared__ float red[3][2];
  const int wid = t >> 6;
  if ((t & 63) == 0) { red[0][wid] = ssp; red[1][wid] = sst; red[2][wid] = dt; }
  __syncthreads();
  const float tp = red[0][0] + red[0][1];
  const float tt = red[1][0] + red[1][1];
  const float td = red[2][0] + red[2][1];
  const float rnp = Q4SCALE / fmaxf(sqrtf(tp), 1e-12f);  // fold quant scale in
  const float rnt = Q4SCALE / fmaxf(sqrtf(tt), 1e-12f);

  const unsigned int pb =
      fp4_enc(a.x * rnp) | (fp4_enc(a.y * rnp) << 4) |
      (fp4_enc(a.z * rnp) << 8) | (fp4_enc(a.w * rnp) << 12);
  const unsigned int tb =
      fp4_enc(b.x * rnt) | (fp4_enc(b.y * rnt) << 4) |
      (fp4_enc(b.z * rnt) << 8) | (fp4_enc(b.w * rnt) << 12);

  // fp4 fragment-tiled destination for the 2 bytes covering k = t*4 .. t*4+3
  const size_t off4 = ((size_t)((n >> 5) * 8 + (t >> 4))) * 1024 +
                      (size_t)(((t >> 3) & 1) * 32 + (n & 31)) * 16 + ((t * 2) & 15);
  *(unsigned short*)(p4 + off4) = (unsigned short)pb;
  *(unsigned short*)(t4 + off4) = (unsigned short)tb;

  if (t == 0) {
    const float inv = 1.0f / (Q4SCALE * Q4SCALE);
    diag[n] = td * rnp * rnt * inv * SCALE;  // exact fp32 diagonal, already scaled
    sumexp[n] = 0.0f;
  }
}

// -------- Kernel B: 256x128-tile MX-fp4 MFMA NT-GEMM (scale 2^-4 both sides),
//          512 threads, 8 waves x 64x64 acc (acc[2][2], 1.0 KB loaded per MFMA
//          vs 1.5 at 32x64 — the r21/r25/r26-measured L1-bytes binder), 4
//          waves/SIMD; ZERO-LDS / ZERO-BARRIER free-run loop, 1-deep prefetch.
__global__ __launch_bounds__(512, 4) void cossim_gemm_lse_v4(
    const unsigned char* __restrict__ P, const unsigned char* __restrict__ T,
    float* __restrict__ sumexp) {
  __shared__ float lds_rs[2][256];  // epilogue row-sum only

  const int tid  = threadIdx.x;
  const int lane = tid & 63;
  const int w    = tid >> 6;   // 0..7
  const int wr   = w >> 1;     // wave row 0..3 (owns 64 C-rows)
  const int wc   = w & 1;      // wave col 0..1 (owns 64 C-cols)

  // L2-locality supertile swizzle, bijective on 2048 blocks = 32by x 64bx tiles.
  // Per XCD: 16by x 16bx region; 4 rounds of 8x8 supertiles
  // (A 8*256rows*256B = 512KB + B 8*128rows*256B = 256KB << 4MB L2).
  const int xcd  = blockIdx.x & 7;
  const int slot = blockIdx.x >> 3;       // 0..255
  const int q    = slot >> 6;             // 0..3: round (2 x 2 supertile grid)
  const int v    = slot & 63;             // 0..63: position in 8x8 supertile
  const int by   = (xcd >> 2) * 16 + (q >> 1) * 8 + (v >> 3);  // 0..31
  const int bx   = (xcd & 3) * 16 + (q & 1) * 8 + (v & 7);     // 0..63
  const int brow = by * 256;

  // Fragment base pointers (fp4, 1KB frag): A row-blocks by*8+wr*2+{0,1};
  // B col-blocks bx*4+wc*2+{0,1}; k-tile s at +s*1024; lane offset lane*16.
  const unsigned char* pa0 = P + ((size_t)(by * 8 + wr * 2 + 0) * 8) * 1024 + lane * 16;
  const unsigned char* pa1 = P + ((size_t)(by * 8 + wr * 2 + 1) * 8) * 1024 + lane * 16;
  const unsigned char* pb0 = T + ((size_t)(bx * 4 + wc * 2 + 0) * 8) * 1024 + lane * 16;
  const unsigned char* pb1 = T + ((size_t)(bx * 4 + wc * 2 + 1) * 8) * 1024 + lane * 16;

  const i32x4 zero4 = {0, 0, 0, 0};
  auto LD = [&](const unsigned char* p) -> i32x8 {
    const i32x4 lo = *(const i32x4*)p;            // 1KB burst — whole fp4 fragment
    return __builtin_shufflevector(lo, zero4, 0, 1, 2, 3, 4, 5, 6, 7);
  };

  f32x16 acc[2][2] = {};

  i32x8 a0 = LD(pa0), a1 = LD(pa1), b0 = LD(pb0), b1 = LD(pb1);

  #pragma unroll
  for (int s = 0; s < 8; ++s) {
    i32x8 na0, na1, nb0, nb1;
    if (s + 1 < 8) {
      const int o = (s + 1) * 1024;
      na0 = LD(pa0 + o); na1 = LD(pa1 + o);
      nb0 = LD(pb0 + o); nb1 = LD(pb1 + o);
    }
    __builtin_amdgcn_s_setprio(1);
    // cbsz=4 (A fmt fp4), blgp=4 (B fmt fp4), scales E8M0 123 = 2^-4 each side
    acc[0][0] = __builtin_amdgcn_mfma_scale_f32_32x32x64_f8f6f4(
        a0, b0, acc[0][0], 4, 4, 0, 123, 0, 123);
    acc[0][1] = __builtin_amdgcn_mfma_scale_f32_32x32x64_f8f6f4(
        a0, b1, acc[0][1], 4, 4, 0, 123, 0, 123);
    acc[1][0] = __builtin_amdgcn_mfma_scale_f32_32x32x64_f8f6f4(
        a1, b0, acc[1][0], 4, 4, 0, 123, 0, 123);
    acc[1][1] = __builtin_amdgcn_mfma_scale_f32_32x32x64_f8f6f4(
        a1, b1, acc[1][1], 4, 4, 0, 123, 0, 123);
    __builtin_amdgcn_s_setprio(0);
    if (s + 1 < 8) { a0 = na0; a1 = na1; b0 = nb0; b1 = nb1; }
  }

  // ---- epilogue: exp + row-sum. C/D 32x32: col=lane&31, row=(r&3)+8*(r>>2)+4*(lane>>5)
  #pragma unroll
  for (int m = 0; m < 2; ++m) {
    #pragma unroll
    for (int r = 0; r < 16; ++r) {
      float x = exp2f(acc[m][0][r] * S2LOG) + exp2f(acc[m][1][r] * S2LOG);
      x += __shfl_xor(x, 1);
      x += __shfl_xor(x, 2);
      x += __shfl_xor(x, 4);
      x += __shfl_xor(x, 8);
      x += __shfl_xor(x, 16);
      if ((lane & 31) == 0)
        lds_rs[wc][wr * 64 + m * 32 + (r & 3) + 8 * (r >> 2) + (lane >> 5) * 4] = x;
    }
  }
  __syncthreads();
  if (tid < 256) {
    atomicAdd(&sumexp[brow + tid], lds_rs[0][tid] + lds_rs[1][tid]);
  }
}

// -------- Kernel C: loss = mean(log(sumexp) - diag), 1024 threads, float4 loads
__global__ __launch_bounds__(1024) void cossim_loss_v3(
    const float* __restrict__ sumexp, const float* __restrict__ diag,
    float* __restrict__ out, int N) {
  const int tid = threadIdx.x;
  const float4* s4 = (const float4*)sumexp;
  const float4* d4 = (const float4*)diag;
  float s = 0.0f;
  for (int i = tid; i < N / 4; i += 1024) {
    float4 a = s4[i];
    float4 b = d4[i];
    s += (logf(a.x) - b.x) + (logf(a.y) - b.y) + (logf(a.z) - b.z) + (logf(a.w) - b.w);
  }
  #pragma unroll
  for (int off = 32; off > 0; off >>= 1) s += __shfl_down(s, off);
  __shared__ float red[16];
  if ((tid & 63) == 0) red[tid >> 6] = s;
  __syncthreads();
  if (tid == 0) {
    float t = 0.0f;
    #pragma unroll
    for (int i = 0; i < 16; ++i) t += red[i];
    out[0] = t / (float)N;
  }
}

extern "C" void kernel_launch(void* const* d_in, const int* in_sizes, int n_in,
                              void* d_out, int out_size, void* d_ws, size_t ws_size,
                              hipStream_t stream) {
  const int C = C_DIM;
  const int N = in_sizes[0] / C;  // 8192
  const float* pred   = (const float*)d_in[0];
  const float* target = (const float*)d_in[1];
  float* out = (float*)d_out;

  char* ws = (char*)d_ws;
  unsigned char* p4 = (unsigned char*)ws;                        // 2 MB fp4 tiled
  unsigned char* t4 = (unsigned char*)(ws + (size_t)N * C / 2);  // 2 MB fp4 tiled
  float* diag   = (float*)(ws + (size_t)N * C);
  float* sumexp = diag + N;

  cossim_normalize_v3<<<N, 128, 0, stream>>>(pred, target, p4, t4, diag, sumexp);
  const int nblk = (N / 256) * (N / 128);  // 2048
  cossim_gemm_lse_v4<<<nblk, 512, 0, stream>>>(p4, t4, sumexp);
  cossim_loss_v3<<<1, 1024, 0, stream>>>(sumexp, diag, out, N);
}

// Round 28
// 105.241 us; speedup vs baseline: 1.0018x; 1.0018x over previous
//
#include <hip/hip_runtime.h>
#include <hip/hip_bf16.h>

typedef __attribute__((ext_vector_type(4))) int   i32x4;
typedef __attribute__((ext_vector_type(8))) int   i32x8;
typedef __attribute__((ext_vector_type(16))) float f32x16;

#define C_DIM 512
#define SCALE 1.6487212707001282f            // exp(0.5)
#define S2LOG (SCALE * 1.4426950408889634f)  // exp(0.5) * log2(e)
#define Q4SCALE 16.0f                        // quantize q = x*16; MFMA scale 2^-4 (E8M0 123)

// e2m1 encode: codes 0..7 = {0,0.5,1,1.5,2,3,4,6}, bit3 = sign
__device__ __forceinline__ unsigned int fp4_enc(float v) {
  unsigned int s = (__float_as_uint(v) >> 28) & 8;
  float a = fabsf(v);
  unsigned int m;
  if      (a < 0.25f) m = 0;
  else if (a < 0.75f) m = 1;
  else if (a < 1.25f) m = 2;
  else if (a < 1.75f) m = 3;
  else if (a < 2.5f)  m = 4;
  else if (a < 3.5f)  m = 5;
  else if (a < 5.0f)  m = 6;
  else                m = 7;
  return s | m;
}

// -------- Kernel A: L2-normalize rows -> MX-fp4 (e2m1, global scale 2^-4) in
//          fragment-tiled layout; exact fp32 diag; zero sumexp.
// fp4 fragment (rb,kb) = 1KB at base (rb*8+kb)*1024 + lane*16;
// lane = 32*(k64half) + (row&31).
__global__ __launch_bounds__(128) void cossim_normalize_v3(
    const float* __restrict__ pred, const float* __restrict__ target,
    unsigned char* __restrict__ p4, unsigned char* __restrict__ t4,
    float* __restrict__ diag, float* __restrict__ sumexp) {
  const int n = blockIdx.x;
  const int t = threadIdx.x;  // 128 threads, 4 floats each = 512
  const float4* p4v = (const float4*)(pred + (size_t)n * C_DIM);
  const float4* q4v = (const float4*)(target + (size_t)n * C_DIM);
  float4 a = p4v[t];
  float4 b = q4v[t];
  float ssp = a.x*a.x + a.y*a.y + a.z*a.z + a.w*a.w;
  float sst = b.x*b.x + b.y*b.y + b.z*b.z + b.w*b.w;
  float dt  = a.x*b.x + a.y*b.y + a.z*b.z + a.w*b.w;
  #pragma unroll
  for (int off = 32; off > 0; off >>= 1) {
    ssp += __shfl_down(ssp, off);
    sst += __shfl_down(sst, off);
    dt  += __shfl_down(dt,  off);
  }
  __shared__ float red[3][2];
  const int wid = t >> 6;
  if ((t & 63) == 0) { red[0][wid] = ssp; red[1][wid] = sst; red[2][wid] = dt; }
  __syncthreads();
  const float tp = red[0][0] + red[0][1];
  const float tt = red[1][0] + red[1][1];
  const float td = red[2][0] + red[2][1];
  const float rnp = Q4SCALE / fmaxf(sqrtf(tp), 1e-12f);  // fold quant scale in
  const float rnt = Q4SCALE / fmaxf(sqrtf(tt), 1e-12f);

  const unsigned int pb =
      fp4_enc(a.x * rnp) | (fp4_enc(a.y * rnp) << 4) |
      (fp4_enc(a.z * rnp) << 8) | (fp4_enc(a.w * rnp) << 12);
  const unsigned int tb =
      fp4_enc(b.x * rnt) | (fp4_enc(b.y * rnt) << 4) |
      (fp4_enc(b.z * rnt) << 8) | (fp4_enc(b.w * rnt) << 12);

  // fp4 fragment-tiled destination for the 2 bytes covering k = t*4 .. t*4+3
  const size_t off4 = ((size_t)((n >> 5) * 8 + (t >> 4))) * 1024 +
                      (size_t)(((t >> 3) & 1) * 32 + (n & 31)) * 16 + ((t * 2) & 15);
  *(unsigned short*)(p4 + off4) = (unsigned short)pb;
  *(unsigned short*)(t4 + off4) = (unsigned short)tb;

  if (t == 0) {
    const float inv = 1.0f / (Q4SCALE * Q4SCALE);
    diag[n] = td * rnp * rnt * inv * SCALE;  // exact fp32 diagonal, already scaled
    sumexp[n] = 0.0f;
  }
}

// -------- Kernel B: 256x128-tile MX-fp4 MFMA NT-GEMM (scale 2^-4 both sides),
//          512 threads, 8 waves x 64x64 acc; fragments stored as i32x4 (fp4 data
//          = 16B/lane; r27 stored i32x8 -> 146-reg demand -> spill). Zero-extend
//          to i32x8 only at the MFMA call site. ZERO-LDS / ZERO-BARRIER loop.
__global__ __launch_bounds__(512, 4) void cossim_gemm_lse_v4(
    const unsigned char* __restrict__ P, const unsigned char* __restrict__ T,
    float* __restrict__ sumexp) {
  __shared__ float lds_rs[2][256];  // epilogue row-sum only

  const int tid  = threadIdx.x;
  const int lane = tid & 63;
  const int w    = tid >> 6;   // 0..7
  const int wr   = w >> 1;     // wave row 0..3 (owns 64 C-rows)
  const int wc   = w & 1;      // wave col 0..1 (owns 64 C-cols)

  // L2-locality supertile swizzle, bijective on 2048 blocks = 32by x 64bx tiles.
  const int xcd  = blockIdx.x & 7;
  const int slot = blockIdx.x >> 3;       // 0..255
  const int q    = slot >> 6;             // 0..3: round (2 x 2 supertile grid)
  const int v    = slot & 63;             // 0..63: position in 8x8 supertile
  const int by   = (xcd >> 2) * 16 + (q >> 1) * 8 + (v >> 3);  // 0..31
  const int bx   = (xcd & 3) * 16 + (q & 1) * 8 + (v & 7);     // 0..63
  const int brow = by * 256;

  // Fragment base pointers (fp4, 1KB frag): A row-blocks by*8+wr*2+{0,1};
  // B col-blocks bx*4+wc*2+{0,1}; k-tile s at +s*1024; lane offset lane*16.
  const unsigned char* pa0 = P + ((size_t)(by * 8 + wr * 2 + 0) * 8) * 1024 + lane * 16;
  const unsigned char* pa1 = P + ((size_t)(by * 8 + wr * 2 + 1) * 8) * 1024 + lane * 16;
  const unsigned char* pb0 = T + ((size_t)(bx * 4 + wc * 2 + 0) * 8) * 1024 + lane * 16;
  const unsigned char* pb1 = T + ((size_t)(bx * 4 + wc * 2 + 1) * 8) * 1024 + lane * 16;

  auto LD4 = [](const unsigned char* p) -> i32x4 {
    return *(const i32x4*)p;                  // 1KB burst — whole fp4 fragment
  };
  const i32x4 z4 = {0, 0, 0, 0};
  auto X8 = [&](i32x4 vq) -> i32x8 {          // zero-extend at call site only
    return __builtin_shufflevector(vq, z4, 0, 1, 2, 3, 4, 5, 6, 7);
  };

  f32x16 acc[2][2] = {};

  i32x4 a0 = LD4(pa0), a1 = LD4(pa1), b0 = LD4(pb0), b1 = LD4(pb1);

  #pragma unroll
  for (int s = 0; s < 8; ++s) {
    i32x4 na0, na1, nb0, nb1;
    if (s + 1 < 8) {
      const int o = (s + 1) * 1024;
      na0 = LD4(pa0 + o); na1 = LD4(pa1 + o);
      nb0 = LD4(pb0 + o); nb1 = LD4(pb1 + o);
    }
    __builtin_amdgcn_s_setprio(1);
    // cbsz=4 (A fmt fp4), blgp=4 (B fmt fp4), scales E8M0 123 = 2^-4 each side
    acc[0][0] = __builtin_amdgcn_mfma_scale_f32_32x32x64_f8f6f4(
        X8(a0), X8(b0), acc[0][0], 4, 4, 0, 123, 0, 123);
    acc[0][1] = __builtin_amdgcn_mfma_scale_f32_32x32x64_f8f6f4(
        X8(a0), X8(b1), acc[0][1], 4, 4, 0, 123, 0, 123);
    acc[1][0] = __builtin_amdgcn_mfma_scale_f32_32x32x64_f8f6f4(
        X8(a1), X8(b0), acc[1][0], 4, 4, 0, 123, 0, 123);
    acc[1][1] = __builtin_amdgcn_mfma_scale_f32_32x32x64_f8f6f4(
        X8(a1), X8(b1), acc[1][1], 4, 4, 0, 123, 0, 123);
    __builtin_amdgcn_s_setprio(0);
    if (s + 1 < 8) { a0 = na0; a1 = na1; b0 = nb0; b1 = nb1; }
  }

  // ---- epilogue: exp + row-sum. C/D 32x32: col=lane&31, row=(r&3)+8*(r>>2)+4*(lane>>5)
  #pragma unroll
  for (int m = 0; m < 2; ++m) {
    #pragma unroll
    for (int r = 0; r < 16; ++r) {
      float x = exp2f(acc[m][0][r] * S2LOG) + exp2f(acc[m][1][r] * S2LOG);
      x += __shfl_xor(x, 1);
      x += __shfl_xor(x, 2);
      x += __shfl_xor(x, 4);
      x += __shfl_xor(x, 8);
      x += __shfl_xor(x, 16);
      if ((lane & 31) == 0)
        lds_rs[wc][wr * 64 + m * 32 + (r & 3) + 8 * (r >> 2) + (lane >> 5) * 4] = x;
    }
  }
  __syncthreads();
  if (tid < 256) {
    atomicAdd(&sumexp[brow + tid], lds_rs[0][tid] + lds_rs[1][tid]);
  }
}

// -------- Kernel C: loss = mean(log(sumexp) - diag), 1024 threads, float4 loads
__global__ __launch_bounds__(1024) void cossim_loss_v3(
    const float* __restrict__ sumexp, const float* __restrict__ diag,
    float* __restrict__ out, int N) {
  const int tid = threadIdx.x;
  const float4* s4 = (const float4*)sumexp;
  const float4* d4 = (const float4*)diag;
  float s = 0.0f;
  for (int i = tid; i < N / 4; i += 1024) {
    float4 a = s4[i];
    float4 b = d4[i];
    s += (logf(a.x) - b.x) + (logf(a.y) - b.y) + (logf(a.z) - b.z) + (logf(a.w) - b.w);
  }
  #pragma unroll
  for (int off = 32; off > 0; off >>= 1) s += __shfl_down(s, off);
  __shared__ float red[16];
  if ((tid & 63) == 0) red[tid >> 6] = s;
  __syncthreads();
  if (tid == 0) {
    float t = 0.0f;
    #pragma unroll
    for (int i = 0; i < 16; ++i) t += red[i];
    out[0] = t / (float)N;
  }
}

extern "C" void kernel_launch(void* const* d_in, const int* in_sizes, int n_in,
                              void* d_out, int out_size, void* d_ws, size_t ws_size,
                              hipStream_t stream) {
  const int C = C_DIM;
  const int N = in_sizes[0] / C;  // 8192
  const float* pred   = (const float*)d_in[0];
  const float* target = (const float*)d_in[1];
  float* out = (float*)d_out;

  char* ws = (char*)d_ws;
  unsigned char* p4 = (unsigned char*)ws;                        // 2 MB fp4 tiled
  unsigned char* t4 = (unsigned char*)(ws + (size_t)N * C / 2);  // 2 MB fp4 tiled
  float* diag   = (float*)(ws + (size_t)N * C);
  float* sumexp = diag + N;

  cossim_normalize_v3<<<N, 128, 0, stream>>>(pred, target, p4, t4, diag, sumexp);
  const int nblk = (N / 256) * (N / 128);  // 2048
  cossim_gemm_lse_v4<<<nblk, 512, 0, stream>>>(p4, t4, sumexp);
  cossim_loss_v3<<<1, 1024, 0, stream>>>(sumexp, diag, out, N);
}

// Round 29
// 63.814 us; speedup vs baseline: 1.6521x; 1.6492x over previous
//
#include <hip/hip_runtime.h>
#include <hip/hip_bf16.h>

typedef __attribute__((ext_vector_type(4))) int   i32x4;
typedef __attribute__((ext_vector_type(8))) int   i32x8;
typedef __attribute__((ext_vector_type(16))) float f32x16;

#define C_DIM 512
#define SCALE 1.6487212707001282f            // exp(0.5)
#define S2LOG (SCALE * 1.4426950408889634f)  // exp(0.5) * log2(e)
#define Q4SCALE 16.0f                        // quantize q = x*16; MFMA scale 2^-4 (E8M0 123)

// e2m1 encode: codes 0..7 = {0,0.5,1,1.5,2,3,4,6}, bit3 = sign
__device__ __forceinline__ unsigned int fp4_enc(float v) {
  unsigned int s = (__float_as_uint(v) >> 28) & 8;
  float a = fabsf(v);
  unsigned int m;
  if      (a < 0.25f) m = 0;
  else if (a < 0.75f) m = 1;
  else if (a < 1.25f) m = 2;
  else if (a < 1.75f) m = 3;
  else if (a < 2.5f)  m = 4;
  else if (a < 3.5f)  m = 5;
  else if (a < 5.0f)  m = 6;
  else                m = 7;
  return s | m;
}

// -------- Kernel A: L2-normalize rows -> MX-fp4 (e2m1, global scale 2^-4) in
//          fragment-tiled layout; exact fp32 diag; zero sumexp.
// fp4 fragment (rb,kb) = 1KB at base (rb*8+kb)*1024 + lane*16;
// lane = 32*(k64half) + (row&31); nibble k'' at byte k''>>1, shift (k''&1)*4.
__global__ __launch_bounds__(128) void cossim_normalize_v3(
    const float* __restrict__ pred, const float* __restrict__ target,
    unsigned char* __restrict__ p4, unsigned char* __restrict__ t4,
    float* __restrict__ diag, float* __restrict__ sumexp) {
  const int n = blockIdx.x;
  const int t = threadIdx.x;  // 128 threads, 4 floats each = 512
  const float4* p4v = (const float4*)(pred + (size_t)n * C_DIM);
  const float4* q4v = (const float4*)(target + (size_t)n * C_DIM);
  float4 a = p4v[t];
  float4 b = q4v[t];
  float ssp = a.x*a.x + a.y*a.y + a.z*a.z + a.w*a.w;
  float sst = b.x*b.x + b.y*b.y + b.z*b.z + b.w*b.w;
  float dt  = a.x*b.x + a.y*b.y + a.z*b.z + a.w*b.w;
  #pragma unroll
  for (int off = 32; off > 0; off >>= 1) {
    ssp += __shfl_down(ssp, off);
    sst += __shfl_down(sst, off);
    dt  += __shfl_down(dt,  off);
  }
  __shared__ float red[3][2];
  const int wid = t >> 6;
  if ((t & 63) == 0) { red[0][wid] = ssp; red[1][wid] = sst; red[2][wid] = dt; }
  __syncthreads();
  const float tp = red[0][0] + red[0][1];
  const float tt = red[1][0] + red[1][1];
  const float td = red[2][0] + red[2][1];
  const float rnp = Q4SCALE / fmaxf(sqrtf(tp), 1e-12f);  // fold quant scale in
  const float rnt = Q4SCALE / fmaxf(sqrtf(tt), 1e-12f);

  const unsigned int pb =
      fp4_enc(a.x * rnp) | (fp4_enc(a.y * rnp) << 4) |
      (fp4_enc(a.z * rnp) << 8) | (fp4_enc(a.w * rnp) << 12);
  const unsigned int tb =
      fp4_enc(b.x * rnt) | (fp4_enc(b.y * rnt) << 4) |
      (fp4_enc(b.z * rnt) << 8) | (fp4_enc(b.w * rnt) << 12);

  // fp4 fragment-tiled destination for the 2 bytes covering k = t*4 .. t*4+3
  const size_t off4 = ((size_t)((n >> 5) * 8 + (t >> 4))) * 1024 +
                      (size_t)(((t >> 3) & 1) * 32 + (n & 31)) * 16 + ((t * 2) & 15);
  *(unsigned short*)(p4 + off4) = (unsigned short)pb;
  *(unsigned short*)(t4 + off4) = (unsigned short)tb;

  if (t == 0) {
    const float inv = 1.0f / (Q4SCALE * Q4SCALE);
    diag[n] = td * rnp * rnt * inv * SCALE;  // exact fp32 diagonal, already scaled
    sumexp[n] = 0.0f;
  }
}

// -------- Kernel B: 128x128-tile MX-fp4 MFMA NT-GEMM (scale 2^-4 both sides),
//          512 threads, 8 waves x 32x64 acc, 4 waves/SIMD; ZERO-LDS/ZERO-BARRIER
//          free-run loop. fp4 fragment = ONE dwordx4/lane (1KB burst). Round-26
//          optimum: 49 us gemm / 61.2 us total; 64x64-wave variants (r27/r28)
//          spill (~146-reg demand from 8-reg MFMA operand tuples) — keep 32x64.
__global__ __launch_bounds__(512, 4) void cossim_gemm_lse_v3(
    const unsigned char* __restrict__ P, const unsigned char* __restrict__ T,
    float* __restrict__ sumexp) {
  __shared__ float lds_rs[2][128];  // epilogue row-sum only

  const int tid  = threadIdx.x;
  const int lane = tid & 63;
  const int w    = tid >> 6;   // 0..7
  const int wr   = w >> 1;     // wave row 0..3 (owns 32 C-rows)
  const int wc   = w & 1;      // wave col 0..1 (owns 64 C-cols)

  // L2-locality supertile swizzle, bijective on 4096 blocks = 64by x 64bx tiles.
  const int xcd  = blockIdx.x & 7;
  const int slot = blockIdx.x >> 3;       // 0..511
  const int q    = slot >> 6;             // 0..7: round (4 x 2 supertile grid)
  const int v    = slot & 63;             // 0..63: position in 8x8 supertile
  const int by   = (xcd >> 2) * 32 + (q >> 1) * 8 + (v >> 3);  // 0..63
  const int bx   = (xcd & 3) * 16 + (q & 1) * 8 + (v & 7);     // 0..63
  const int brow = by * 128;

  // Fragment base pointers (fp4): base (rb*8+s)*1024; lane offset lane*16.
  const unsigned char* pa  = P + ((size_t)(by * 4 + wr) * 8) * 1024 + lane * 16;
  const unsigned char* pb0 = T + ((size_t)(bx * 4 + wc * 2 + 0) * 8) * 1024 + lane * 16;
  const unsigned char* pb1 = T + ((size_t)(bx * 4 + wc * 2 + 1) * 8) * 1024 + lane * 16;

  const i32x4 zero4 = {0, 0, 0, 0};
  auto LD = [&](const unsigned char* p) -> i32x8 {
    const i32x4 lo = *(const i32x4*)p;            // 1KB burst — whole fp4 fragment
    return __builtin_shufflevector(lo, zero4, 0, 1, 2, 3, 4, 5, 6, 7);
  };

  f32x16 acc0 = {}, acc1 = {};

  i32x8 a0 = LD(pa), b0 = LD(pb0), b1 = LD(pb1);

  #pragma unroll
  for (int s = 0; s < 8; ++s) {
    i32x8 na, nb0, nb1;
    if (s + 1 < 8) {
      const int o = (s + 1) * 1024;
      na = LD(pa + o); nb0 = LD(pb0 + o); nb1 = LD(pb1 + o);
    }
    __builtin_amdgcn_s_setprio(1);
    // cbsz=4 (A fmt fp4), blgp=4 (B fmt fp4), scales E8M0 123 = 2^-4 each side
    acc0 = __builtin_amdgcn_mfma_scale_f32_32x32x64_f8f6f4(
        a0, b0, acc0, 4, 4, 0, 123, 0, 123);
    acc1 = __builtin_amdgcn_mfma_scale_f32_32x32x64_f8f6f4(
        a0, b1, acc1, 4, 4, 0, 123, 0, 123);
    __builtin_amdgcn_s_setprio(0);
    if (s + 1 < 8) { a0 = na; b0 = nb0; b1 = nb1; }
  }

  // ---- epilogue: exp + row-sum. C/D 32x32: col=lane&31, row=(r&3)+8*(r>>2)+4*(lane>>5)
  #pragma unroll
  for (int r = 0; r < 16; ++r) {
    float x = exp2f(acc0[r] * S2LOG) + exp2f(acc1[r] * S2LOG);
    x += __shfl_xor(x, 1);
    x += __shfl_xor(x, 2);
    x += __shfl_xor(x, 4);
    x += __shfl_xor(x, 8);
    x += __shfl_xor(x, 16);
    if ((lane & 31) == 0)
      lds_rs[wc][wr * 32 + (r & 3) + 8 * (r >> 2) + (lane >> 5) * 4] = x;
  }
  __syncthreads();
  if (tid < 128) {
    atomicAdd(&sumexp[brow + tid], lds_rs[0][tid] + lds_rs[1][tid]);
  }
}

// -------- Kernel C: loss = mean(log(sumexp) - diag), 1024 threads, float4 loads
__global__ __launch_bounds__(1024) void cossim_loss_v3(
    const float* __restrict__ sumexp, const float* __restrict__ diag,
    float* __restrict__ out, int N) {
  const int tid = threadIdx.x;
  const float4* s4 = (const float4*)sumexp;
  const float4* d4 = (const float4*)diag;
  float s = 0.0f;
  for (int i = tid; i < N / 4; i += 1024) {
    float4 a = s4[i];
    float4 b = d4[i];
    s += (logf(a.x) - b.x) + (logf(a.y) - b.y) + (logf(a.z) - b.z) + (logf(a.w) - b.w);
  }
  #pragma unroll
  for (int off = 32; off > 0; off >>= 1) s += __shfl_down(s, off);
  __shared__ float red[16];
  if ((tid & 63) == 0) red[tid >> 6] = s;
  __syncthreads();
  if (tid == 0) {
    float t = 0.0f;
    #pragma unroll
    for (int i = 0; i < 16; ++i) t += red[i];
    out[0] = t / (float)N;
  }
}

extern "C" void kernel_launch(void* const* d_in, const int* in_sizes, int n_in,
                              void* d_out, int out_size, void* d_ws, size_t ws_size,
                              hipStream_t stream) {
  const int C = C_DIM;
  const int N = in_sizes[0] / C;  // 8192
  const float* pred   = (const float*)d_in[0];
  const float* target = (const float*)d_in[1];
  float* out = (float*)d_out;

  char* ws = (char*)d_ws;
  unsigned char* p4 = (unsigned char*)ws;                        // 2 MB fp4 tiled
  unsigned char* t4 = (unsigned char*)(ws + (size_t)N * C / 2);  // 2 MB fp4 tiled
  float* diag   = (float*)(ws + (size_t)N * C);
  float* sumexp = diag + N;

  cossim_normalize_v3<<<N, 128, 0, stream>>>(pred, target, p4, t4, diag, sumexp);
  const int nblk = (N / 128) * (N / 128);  // 4096
  cossim_gemm_lse_v3<<<nblk, 512, 0, stream>>>(p4, t4, sumexp);
  cossim_loss_v3<<<1, 1024, 0, stream>>>(sumexp, diag, out, N);
}

// Round 30
// 62.955 us; speedup vs baseline: 1.6746x; 1.0136x over previous
//
#include <hip/hip_runtime.h>
#include <hip/hip_bf16.h>

typedef __attribute__((ext_vector_type(4))) int   i32x4;
typedef __attribute__((ext_vector_type(8))) int   i32x8;
typedef __attribute__((ext_vector_type(16))) float f32x16;

#define C_DIM 512
#define SCALE 1.6487212707001282f            // exp(0.5)
#define S2LOG (SCALE * 1.4426950408889634f)  // exp(0.5) * log2(e)
#define Q4SCALE 16.0f                        // quantize q = x*16; MFMA scale 2^-4 (E8M0 123)

// e2m1 encode: codes 0..7 = {0,0.5,1,1.5,2,3,4,6}, bit3 = sign
__device__ __forceinline__ unsigned int fp4_enc(float v) {
  unsigned int s = (__float_as_uint(v) >> 28) & 8;
  float a = fabsf(v);
  unsigned int m;
  if      (a < 0.25f) m = 0;
  else if (a < 0.75f) m = 1;
  else if (a < 1.25f) m = 2;
  else if (a < 1.75f) m = 3;
  else if (a < 2.5f)  m = 4;
  else if (a < 3.5f)  m = 5;
  else if (a < 5.0f)  m = 6;
  else                m = 7;
  return s | m;
}

// -------- Kernel A: L2-normalize rows -> MX-fp4 (e2m1, global scale 2^-4) in
//          fragment-tiled layout; exact fp32 diag; zero sumexp.
// fp4 fragment (rb,kb) = 1KB at base (rb*8+kb)*1024 + lane*16;
// lane = 32*(k64half) + (row&31).
__global__ __launch_bounds__(128) void cossim_normalize_v3(
    const float* __restrict__ pred, const float* __restrict__ target,
    unsigned char* __restrict__ p4, unsigned char* __restrict__ t4,
    float* __restrict__ diag, float* __restrict__ sumexp) {
  const int n = blockIdx.x;
  const int t = threadIdx.x;  // 128 threads, 4 floats each = 512
  const float4* p4v = (const float4*)(pred + (size_t)n * C_DIM);
  const float4* q4v = (const float4*)(target + (size_t)n * C_DIM);
  float4 a = p4v[t];
  float4 b = q4v[t];
  float ssp = a.x*a.x + a.y*a.y + a.z*a.z + a.w*a.w;
  float sst = b.x*b.x + b.y*b.y + b.z*b.z + b.w*b.w;
  float dt  = a.x*b.x + a.y*b.y + a.z*b.z + a.w*b.w;
  #pragma unroll
  for (int off = 32; off > 0; off >>= 1) {
    ssp += __shfl_down(ssp, off);
    sst += __shfl_down(sst, off);
    dt  += __shfl_down(dt,  off);
  }
  __shared__ float red[3][2];
  const int wid = t >> 6;
  if ((t & 63) == 0) { red[0][wid] = ssp; red[1][wid] = sst; red[2][wid] = dt; }
  __syncthreads();
  const float tp = red[0][0] + red[0][1];
  const float tt = red[1][0] + red[1][1];
  const float td = red[2][0] + red[2][1];
  const float rnp = Q4SCALE / fmaxf(sqrtf(tp), 1e-12f);  // fold quant scale in
  const float rnt = Q4SCALE / fmaxf(sqrtf(tt), 1e-12f);

  const unsigned int pb =
      fp4_enc(a.x * rnp) | (fp4_enc(a.y * rnp) << 4) |
      (fp4_enc(a.z * rnp) << 8) | (fp4_enc(a.w * rnp) << 12);
  const unsigned int tb =
      fp4_enc(b.x * rnt) | (fp4_enc(b.y * rnt) << 4) |
      (fp4_enc(b.z * rnt) << 8) | (fp4_enc(b.w * rnt) << 12);

  // fp4 fragment-tiled destination for the 2 bytes covering k = t*4 .. t*4+3
  const size_t off4 = ((size_t)((n >> 5) * 8 + (t >> 4))) * 1024 +
                      (size_t)(((t >> 3) & 1) * 32 + (n & 31)) * 16 + ((t * 2) & 15);
  *(unsigned short*)(p4 + off4) = (unsigned short)pb;
  *(unsigned short*)(t4 + off4) = (unsigned short)tb;

  if (t == 0) {
    const float inv = 1.0f / (Q4SCALE * Q4SCALE);
    diag[n] = td * rnp * rnt * inv * SCALE;  // exact fp32 diagonal, already scaled
    sumexp[n] = 0.0f;
  }
}

// -------- Kernel B: 128x128-tile MX-fp4 MFMA NT-GEMM (scale 2^-4 both sides),
//          512 threads, 8 waves x 32x64 acc, 4 waves/SIMD; ZERO-LDS/ZERO-BARRIER
//          free-run loop. PING-PONG persistent i32x8 tuples (highs zeroed once,
//          prefetch loads write directly into the inactive tuple's low half) —
//          removes the per-iteration zero-extend/rotation movs behind r29's 48%
//          VALUBusy. Ledger: 48 tuple VGPR + ~20 addr + 32 AGPR = ~100 <= 128.
__global__ __launch_bounds__(512, 4) void cossim_gemm_lse_v3(
    const unsigned char* __restrict__ P, const unsigned char* __restrict__ T,
    float* __restrict__ sumexp) {
  __shared__ float lds_rs[2][128];  // epilogue row-sum only

  const int tid  = threadIdx.x;
  const int lane = tid & 63;
  const int w    = tid >> 6;   // 0..7
  const int wr   = w >> 1;     // wave row 0..3 (owns 32 C-rows)
  const int wc   = w & 1;      // wave col 0..1 (owns 64 C-cols)

  // L2-locality supertile swizzle, bijective on 4096 blocks = 64by x 64bx tiles.
  const int xcd  = blockIdx.x & 7;
  const int slot = blockIdx.x >> 3;       // 0..511
  const int q    = slot >> 6;             // 0..7: round (4 x 2 supertile grid)
  const int v    = slot & 63;             // 0..63: position in 8x8 supertile
  const int by   = (xcd >> 2) * 32 + (q >> 1) * 8 + (v >> 3);  // 0..63
  const int bx   = (xcd & 3) * 16 + (q & 1) * 8 + (v & 7);     // 0..63
  const int brow = by * 128;

  // Fragment base pointers (fp4): base (rb*8+s)*1024; lane offset lane*16.
  const unsigned char* pa  = P + ((size_t)(by * 4 + wr) * 8) * 1024 + lane * 16;
  const unsigned char* pb0 = T + ((size_t)(bx * 4 + wc * 2 + 0) * 8) * 1024 + lane * 16;
  const unsigned char* pb1 = T + ((size_t)(bx * 4 + wc * 2 + 1) * 8) * 1024 + lane * 16;

  f32x16 acc0 = {}, acc1 = {};

  // Ping-pong tuple sets; upper halves zeroed ONCE (fp4 data = low 4 regs only).
  i32x8 fA[2], fB0[2], fB1[2];
  #pragma unroll
  for (int j = 0; j < 8; ++j) {
    fA[0][j] = 0; fA[1][j] = 0;
    fB0[0][j] = 0; fB0[1][j] = 0;
    fB1[0][j] = 0; fB1[1][j] = 0;
  }
  *(i32x4*)&fA[0]  = *(const i32x4*)pa;
  *(i32x4*)&fB0[0] = *(const i32x4*)pb0;
  *(i32x4*)&fB1[0] = *(const i32x4*)pb1;

  #pragma unroll
  for (int s = 0; s < 8; ++s) {
    const int cur = s & 1;
    const int nxt = cur ^ 1;
    if (s + 1 < 8) {
      const int o = (s + 1) * 1024;
      *(i32x4*)&fA[nxt]  = *(const i32x4*)(pa + o);
      *(i32x4*)&fB0[nxt] = *(const i32x4*)(pb0 + o);
      *(i32x4*)&fB1[nxt] = *(const i32x4*)(pb1 + o);
    }
    __builtin_amdgcn_s_setprio(1);
    // cbsz=4 (A fmt fp4), blgp=4 (B fmt fp4), scales E8M0 123 = 2^-4 each side
    acc0 = __builtin_amdgcn_mfma_scale_f32_32x32x64_f8f6f4(
        fA[cur], fB0[cur], acc0, 4, 4, 0, 123, 0, 123);
    acc1 = __builtin_amdgcn_mfma_scale_f32_32x32x64_f8f6f4(
        fA[cur], fB1[cur], acc1, 4, 4, 0, 123, 0, 123);
    __builtin_amdgcn_s_setprio(0);
  }

  // ---- epilogue: exp + row-sum. C/D 32x32: col=lane&31, row=(r&3)+8*(r>>2)+4*(lane>>5)
  #pragma unroll
  for (int r = 0; r < 16; ++r) {
    float x = exp2f(acc0[r] * S2LOG) + exp2f(acc1[r] * S2LOG);
    x += __shfl_xor(x, 1);
    x += __shfl_xor(x, 2);
    x += __shfl_xor(x, 4);
    x += __shfl_xor(x, 8);
    x += __shfl_xor(x, 16);
    if ((lane & 31) == 0)
      lds_rs[wc][wr * 32 + (r & 3) + 8 * (r >> 2) + (lane >> 5) * 4] = x;
  }
  __syncthreads();
  if (tid < 128) {
    atomicAdd(&sumexp[brow + tid], lds_rs[0][tid] + lds_rs[1][tid]);
  }
}

// -------- Kernel C: loss = mean(log(sumexp) - diag), 1024 threads, float4 loads
__global__ __launch_bounds__(1024) void cossim_loss_v3(
    const float* __restrict__ sumexp, const float* __restrict__ diag,
    float* __restrict__ out, int N) {
  const int tid = threadIdx.x;
  const float4* s4 = (const float4*)sumexp;
  const float4* d4 = (const float4*)diag;
  float s = 0.0f;
  for (int i = tid; i < N / 4; i += 1024) {
    float4 a = s4[i];
    float4 b = d4[i];
    s += (logf(a.x) - b.x) + (logf(a.y) - b.y) + (logf(a.z) - b.z) + (logf(a.w) - b.w);
  }
  #pragma unroll
  for (int off = 32; off > 0; off >>= 1) s += __shfl_down(s, off);
  __shared__ float red[16];
  if ((tid & 63) == 0) red[tid >> 6] = s;
  __syncthreads();
  if (tid == 0) {
    float t = 0.0f;
    #pragma unroll
    for (int i = 0; i < 16; ++i) t += red[i];
    out[0] = t / (float)N;
  }
}

extern "C" void kernel_launch(void* const* d_in, const int* in_sizes, int n_in,
                              void* d_out, int out_size, void* d_ws, size_t ws_size,
                              hipStream_t stream) {
  const int C = C_DIM;
  const int N = in_sizes[0] / C;  // 8192
  const float* pred   = (const float*)d_in[0];
  const float* target = (const float*)d_in[1];
  float* out = (float*)d_out;

  char* ws = (char*)d_ws;
  unsigned char* p4 = (unsigned char*)ws;                        // 2 MB fp4 tiled
  unsigned char* t4 = (unsigned char*)(ws + (size_t)N * C / 2);  // 2 MB fp4 tiled
  float* diag   = (float*)(ws + (size_t)N * C);
  float* sumexp = diag + N;

  cossim_normalize_v3<<<N, 128, 0, stream>>>(pred, target, p4, t4, diag, sumexp);
  const int nblk = (N / 128) * (N / 128);  // 4096
  cossim_gemm_lse_v3<<<nblk, 512, 0, stream>>>(p4, t4, sumexp);
  cossim_loss_v3<<<1, 1024, 0, stream>>>(sumexp, diag, out, N);
}

// Round 31
// 56.569 us; speedup vs baseline: 1.8637x; 1.1129x over previous
//
#include <hip/hip_runtime.h>
#include <hip/hip_bf16.h>

typedef __attribute__((ext_vector_type(4))) int   i32x4;
typedef __attribute__((ext_vector_type(8))) int   i32x8;
typedef __attribute__((ext_vector_type(16))) float f32x16;

#define C_DIM 512
#define SCALE 1.6487212707001282f            // exp(0.5)
#define S2LOG (SCALE * 1.4426950408889634f)  // exp(0.5) * log2(e)
#define Q4SCALE 16.0f                        // quantize q = x*16; MFMA scale 2^-4 (E8M0 123)

// e2m1 encode: codes 0..7 = {0,0.5,1,1.5,2,3,4,6}, bit3 = sign
__device__ __forceinline__ unsigned int fp4_enc(float v) {
  unsigned int s = (__float_as_uint(v) >> 28) & 8;
  float a = fabsf(v);
  unsigned int m;
  if      (a < 0.25f) m = 0;
  else if (a < 0.75f) m = 1;
  else if (a < 1.25f) m = 2;
  else if (a < 1.75f) m = 3;
  else if (a < 2.5f)  m = 4;
  else if (a < 3.5f)  m = 5;
  else if (a < 5.0f)  m = 6;
  else                m = 7;
  return s | m;
}

// -------- Kernel A: L2-normalize rows -> MX-fp4 (e2m1, global scale 2^-4) in
//          fragment-tiled layout; exact fp32 diag; zero sumexp.
//          WAVE-PER-ROW: 64 lanes x 8 elems, full shuffle butterfly — no LDS,
//          no __syncthreads; one 4B store per buffer per lane.
// fp4 fragment (rb,kb) = 1KB at base (rb*8+kb)*1024 + lanef*16;
// lanef = 32*k64half + (row&31); k-byte (k&31)/2 within the 16B chunk.
__global__ __launch_bounds__(256) void cossim_normalize_v4(
    const float* __restrict__ pred, const float* __restrict__ target,
    unsigned char* __restrict__ p4, unsigned char* __restrict__ t4,
    float* __restrict__ diag, float* __restrict__ sumexp) {
  const int n = blockIdx.x * 4 + (threadIdx.x >> 6);  // 4 rows per block
  const int l = threadIdx.x & 63;                     // lane owns k = l*8 .. l*8+7
  const float4* pv = (const float4*)(pred + (size_t)n * C_DIM);
  const float4* qv = (const float4*)(target + (size_t)n * C_DIM);
  const float4 a0 = pv[l * 2], a1 = pv[l * 2 + 1];
  const float4 b0 = qv[l * 2], b1 = qv[l * 2 + 1];

  float ssp = a0.x*a0.x + a0.y*a0.y + a0.z*a0.z + a0.w*a0.w +
              a1.x*a1.x + a1.y*a1.y + a1.z*a1.z + a1.w*a1.w;
  float sst = b0.x*b0.x + b0.y*b0.y + b0.z*b0.z + b0.w*b0.w +
              b1.x*b1.x + b1.y*b1.y + b1.z*b1.z + b1.w*b1.w;
  float dt  = a0.x*b0.x + a0.y*b0.y + a0.z*b0.z + a0.w*b0.w +
              a1.x*b1.x + a1.y*b1.y + a1.z*b1.z + a1.w*b1.w;
  #pragma unroll
  for (int off = 32; off > 0; off >>= 1) {  // butterfly: all lanes get totals
    ssp += __shfl_xor(ssp, off);
    sst += __shfl_xor(sst, off);
    dt  += __shfl_xor(dt,  off);
  }
  const float rnp = Q4SCALE / fmaxf(sqrtf(ssp), 1e-12f);
  const float rnt = Q4SCALE / fmaxf(sqrtf(sst), 1e-12f);

  const unsigned int pw =
      fp4_enc(a0.x * rnp)        | (fp4_enc(a0.y * rnp) << 4)  |
      (fp4_enc(a0.z * rnp) << 8) | (fp4_enc(a0.w * rnp) << 12) |
      (fp4_enc(a1.x * rnp) << 16)| (fp4_enc(a1.y * rnp) << 20) |
      (fp4_enc(a1.z * rnp) << 24)| (fp4_enc(a1.w * rnp) << 28);
  const unsigned int tw =
      fp4_enc(b0.x * rnt)        | (fp4_enc(b0.y * rnt) << 4)  |
      (fp4_enc(b0.z * rnt) << 8) | (fp4_enc(b0.w * rnt) << 12) |
      (fp4_enc(b1.x * rnt) << 16)| (fp4_enc(b1.y * rnt) << 20) |
      (fp4_enc(b1.z * rnt) << 24)| (fp4_enc(b1.w * rnt) << 28);

  // k = l*8: kb = l>>3, k64half = (l>>2)&1, byte within chunk = (l&3)*4
  const size_t off4 = ((size_t)((n >> 5) * 8 + (l >> 3))) * 1024 +
                      (size_t)(((l >> 2) & 1) * 32 + (n & 31)) * 16 + (l & 3) * 4;
  *(unsigned int*)(p4 + off4) = pw;
  *(unsigned int*)(t4 + off4) = tw;

  if (l == 0) {
    const float inv = 1.0f / (Q4SCALE * Q4SCALE);
    diag[n] = dt * rnp * rnt * inv * SCALE;  // exact fp32 diagonal, already scaled
    sumexp[n] = 0.0f;
  }
}

// -------- Kernel B: 128x128-tile MX-fp4 MFMA NT-GEMM (scale 2^-4 both sides),
//          512 threads, 8 waves x 32x64 acc, 4 waves/SIMD; ZERO-LDS/ZERO-BARRIER
//          free-run loop. fp4 fragment = ONE dwordx4/lane (1KB burst).
//          setprio removed (m190: null-to-negative on non-phase-split GEMM).
__global__ __launch_bounds__(512, 4) void cossim_gemm_lse_v3(
    const unsigned char* __restrict__ P, const unsigned char* __restrict__ T,
    float* __restrict__ sumexp) {
  __shared__ float lds_rs[2][128];  // epilogue row-sum only

  const int tid  = threadIdx.x;
  const int lane = tid & 63;
  const int w    = tid >> 6;   // 0..7
  const int wr   = w >> 1;     // wave row 0..3 (owns 32 C-rows)
  const int wc   = w & 1;      // wave col 0..1 (owns 64 C-cols)

  // L2-locality supertile swizzle, bijective on 4096 blocks = 64by x 64bx tiles.
  const int xcd  = blockIdx.x & 7;
  const int slot = blockIdx.x >> 3;       // 0..511
  const int q    = slot >> 6;             // 0..7: round (4 x 2 supertile grid)
  const int v    = slot & 63;             // 0..63: position in 8x8 supertile
  const int by   = (xcd >> 2) * 32 + (q >> 1) * 8 + (v >> 3);  // 0..63
  const int bx   = (xcd & 3) * 16 + (q & 1) * 8 + (v & 7);     // 0..63
  const int brow = by * 128;

  // Fragment base pointers (fp4): base (rb*8+s)*1024; lane offset lane*16.
  const unsigned char* pa  = P + ((size_t)(by * 4 + wr) * 8) * 1024 + lane * 16;
  const unsigned char* pb0 = T + ((size_t)(bx * 4 + wc * 2 + 0) * 8) * 1024 + lane * 16;
  const unsigned char* pb1 = T + ((size_t)(bx * 4 + wc * 2 + 1) * 8) * 1024 + lane * 16;

  const i32x4 zero4 = {0, 0, 0, 0};
  auto LD = [&](const unsigned char* p) -> i32x8 {
    const i32x4 lo = *(const i32x4*)p;            // 1KB burst — whole fp4 fragment
    return __builtin_shufflevector(lo, zero4, 0, 1, 2, 3, 4, 5, 6, 7);
  };

  f32x16 acc0 = {}, acc1 = {};

  i32x8 a0 = LD(pa), b0 = LD(pb0), b1 = LD(pb1);

  #pragma unroll
  for (int s = 0; s < 8; ++s) {
    i32x8 na, nb0, nb1;
    if (s + 1 < 8) {
      const int o = (s + 1) * 1024;
      na = LD(pa + o); nb0 = LD(pb0 + o); nb1 = LD(pb1 + o);
    }
    // cbsz=4 (A fmt fp4), blgp=4 (B fmt fp4), scales E8M0 123 = 2^-4 each side
    acc0 = __builtin_amdgcn_mfma_scale_f32_32x32x64_f8f6f4(
        a0, b0, acc0, 4, 4, 0, 123, 0, 123);
    acc1 = __builtin_amdgcn_mfma_scale_f32_32x32x64_f8f6f4(
        a0, b1, acc1, 4, 4, 0, 123, 0, 123);
    if (s + 1 < 8) { a0 = na; b0 = nb0; b1 = nb1; }
  }

  // ---- epilogue: exp + row-sum. C/D 32x32: col=lane&31, row=(r&3)+8*(r>>2)+4*(lane>>5)
  #pragma unroll
  for (int r = 0; r < 16; ++r) {
    float x = exp2f(acc0[r] * S2LOG) + exp2f(acc1[r] * S2LOG);
    x += __shfl_xor(x, 1);
    x += __shfl_xor(x, 2);
    x += __shfl_xor(x, 4);
    x += __shfl_xor(x, 8);
    x += __shfl_xor(x, 16);
    if ((lane & 31) == 0)
      lds_rs[wc][wr * 32 + (r & 3) + 8 * (r >> 2) + (lane >> 5) * 4] = x;
  }
  __syncthreads();
  if (tid < 128) {
    atomicAdd(&sumexp[brow + tid], lds_rs[0][tid] + lds_rs[1][tid]);
  }
}

// -------- Kernel C: loss = mean(log(sumexp) - diag), 1024 threads, float4 loads
__global__ __launch_bounds__(1024) void cossim_loss_v3(
    const float* __restrict__ sumexp, const float* __restrict__ diag,
    float* __restrict__ out, int N) {
  const int tid = threadIdx.x;
  const float4* s4 = (const float4*)sumexp;
  const float4* d4 = (const float4*)diag;
  float s = 0.0f;
  for (int i = tid; i < N / 4; i += 1024) {
    float4 a = s4[i];
    float4 b = d4[i];
    s += (logf(a.x) - b.x) + (logf(a.y) - b.y) + (logf(a.z) - b.z) + (logf(a.w) - b.w);
  }
  #pragma unroll
  for (int off = 32; off > 0; off >>= 1) s += __shfl_down(s, off);
  __shared__ float red[16];
  if ((tid & 63) == 0) red[tid >> 6] = s;
  __syncthreads();
  if (tid == 0) {
    float t = 0.0f;
    #pragma unroll
    for (int i = 0; i < 16; ++i) t += red[i];
    out[0] = t / (float)N;
  }
}

extern "C" void kernel_launch(void* const* d_in, const int* in_sizes, int n_in,
                              void* d_out, int out_size, void* d_ws, size_t ws_size,
                              hipStream_t stream) {
  const int C = C_DIM;
  const int N = in_sizes[0] / C;  // 8192
  const float* pred   = (const float*)d_in[0];
  const float* target = (const float*)d_in[1];
  float* out = (float*)d_out;

  char* ws = (char*)d_ws;
  unsigned char* p4 = (unsigned char*)ws;                        // 2 MB fp4 tiled
  unsigned char* t4 = (unsigned char*)(ws + (size_t)N * C / 2);  // 2 MB fp4 tiled
  float* diag   = (float*)(ws + (size_t)N * C);
  float* sumexp = diag + N;

  cossim_normalize_v4<<<N / 4, 256, 0, stream>>>(pred, target, p4, t4, diag, sumexp);
  const int nblk = (N / 128) * (N / 128);  // 4096
  cossim_gemm_lse_v3<<<nblk, 512, 0, stream>>>(p4, t4, sumexp);
  cossim_loss_v3<<<1, 1024, 0, stream>>>(sumexp, diag, out, N);
}